// Round 10
// baseline (491.028 us; speedup 1.0000x reference)
//
#include <hip/hip_runtime.h>
#include <hip/hip_bf16.h>
#include <math.h>

#define NN 50000
#define NNP 50048  // padded to multiple of 128
#define NE 800000
#define DIN1 64
#define NHEAD 4
#define CH 32
#define HC 128
#define EDIM 16
#define NG 2000
#define MAXCH 64  // edge chunk per node-wave

typedef __attribute__((ext_vector_type(8))) short short8;
typedef __attribute__((ext_vector_type(4))) float floatx4;

__device__ __forceinline__ float lrelu(float x, float s) { return x > 0.f ? x : s * x; }

__device__ __forceinline__ unsigned short f2bf(float x) {
  unsigned int u = __float_as_uint(x);
  u += 0x7fff + ((u >> 16) & 1);  // RNE
  return (unsigned short)(u >> 16);
}
__device__ __forceinline__ float bflo(unsigned int u) { return __uint_as_float(u << 16); }
__device__ __forceinline__ float bfhi(unsigned int u) { return __uint_as_float(u & 0xffff0000u); }

// async global->LDS: per-lane 16B from lane's own gptr; LDS dest = wave-uniform base + lane*16.
__device__ __forceinline__ void async16(void* lds, const void* g) {
  __builtin_amdgcn_global_load_lds((const __attribute__((address_space(1))) unsigned int*)g,
                                   (__attribute__((address_space(3))) unsigned int*)lds, 16, 0, 0);
}

// ================= merged prep kernel: we_a | wsd | lw1t | wt | cast | gstart | outinit | hist
#define NB_WEA 1
#define NB_WSD 24
#define NB_LW1T 768
#define NB_WT 160
#define NB_CAST 12500
#define NB_GST 196
#define NB_OUT 196
#define NB_HIST 3125
#define PREP_BLOCKS (NB_WEA + NB_WSD + NB_LW1T + NB_WT + NB_CAST + NB_GST + NB_OUT + NB_HIST)

__global__ __launch_bounds__(256) void k_prep(
    const float* __restrict__ We1, const float* __restrict__ ae1,
    const float* __restrict__ We2, const float* __restrict__ ae2,
    const float* __restrict__ We3, const float* __restrict__ ae3, float* __restrict__ wea,
    const float* __restrict__ W1, const float* __restrict__ as1, const float* __restrict__ ad1,
    const float* __restrict__ W2, const float* __restrict__ as2, const float* __restrict__ ad2,
    const float* __restrict__ W3, const float* __restrict__ as3, const float* __restrict__ ad3,
    unsigned short* __restrict__ wsdb,
    const float* __restrict__ lw1, unsigned short* __restrict__ lw1img,
    unsigned short* __restrict__ wtb,
    const float* __restrict__ x, unsigned short* __restrict__ xb0,
    const int* __restrict__ batch, int* __restrict__ gs,
    float* __restrict__ out, const float* __restrict__ lb2,
    const int* __restrict__ dstp, int* __restrict__ cnt) {
  int b = blockIdx.x;
  int t = threadIdx.x;
  if (b < NB_WEA) {
    if (t >= 3 * EDIM * NHEAD) return;
    int l = t / (EDIM * NHEAD);
    int rem = t % (EDIM * NHEAD);
    int d = rem / NHEAD, h = rem % NHEAD;
    const float* We = (l == 0) ? We1 : ((l == 1) ? We2 : We3);
    const float* ae = (l == 0) ? ae1 : ((l == 1) ? ae2 : ae3);
    float s = 0.f;
    for (int c = 0; c < CH; ++c) s += We[d * HC + h * CH + c] * ae[h * CH + c];
    wea[t] = s;
    return;
  }
  b -= NB_WEA;
  if (b < NB_WSD) {
    int i = b * 256 + t;
    int l = i >> 11;
    int col = (i >> 7) & 15;
    int k = i & 127;
    size_t oidx = (size_t)l * 2048 + ((size_t)(k >> 3) * 16 + col) * 8 + (k & 7);
    if (col >= 8 || (l == 0 && k >= DIN1)) { wsdb[oidx] = 0; return; }
    const float* W = (l == 0) ? W1 : ((l == 1) ? W2 : W3);
    int head = col & 3;
    const float* av = (col < 4) ? ((l == 0) ? as1 : ((l == 1) ? as2 : as3))
                                : ((l == 0) ? ad1 : ((l == 1) ? ad2 : ad3));
    float s = 0.f;
    for (int c = 0; c < CH; ++c) s += W[(size_t)k * HC + head * CH + c] * av[head * CH + c];
    wsdb[oidx] = f2bf(s);
    return;
  }
  b -= NB_WSD;
  if (b < NB_LW1T) {
    int i = b * 256 + t;
    int j = i / 384, k = i % 384;
    int jh = j >> 8, jc = j & 255;
    lw1img[((size_t)jh * 48 * 256 + (size_t)(k >> 3) * 256 + jc) * 8 + (k & 7)] =
        f2bf(lw1[(size_t)k * 512 + j]);
    return;
  }
  b -= NB_LW1T;
  if (b < NB_WT) {
    int i = b * 256 + t;
    const float* W;
    int j, k;
    size_t base;
    if (i < 128 * 64) {
      W = W1; j = i / 64; k = i % 64; base = 0;
    } else if (i < 128 * 64 + 128 * 128) {
      int ii = i - 128 * 64;
      W = W2; j = ii / 128; k = ii % 128; base = 8192;
    } else {
      int ii = i - (128 * 64 + 128 * 128);
      W = W3; j = ii / 128; k = ii % 128; base = 24576;
    }
    wtb[base + ((size_t)(k >> 3) * 128 + j) * 8 + (k & 7)] = f2bf(W[(size_t)k * HC + j]);
    return;
  }
  b -= NB_WT;
  if (b < NB_CAST) {
    int i = b * 256 + t;
    int n = i >> 6, k = i & 63;
    xb0[((size_t)(k >> 3) * NNP + n) * 8 + (k & 7)] = f2bf(x[i]);
    return;
  }
  b -= NB_CAST;
  if (b < NB_GST) {
    int i = b * 256 + t;
    if (i >= NN) return;
    int bb = batch[i];
    if (i == 0) {
      for (int g = 0; g <= bb; ++g) gs[g] = 0;
    } else {
      int pb = batch[i - 1];
      for (int g = pb + 1; g <= bb; ++g) gs[g] = i;
    }
    if (i == NN - 1) {
      for (int g = bb + 1; g <= NG; ++g) gs[g] = NN;
    }
    return;
  }
  b -= NB_GST;
  if (b < NB_OUT) {
    int i = b * 256 + t;
    if (i < NN) out[i] = lb2[0];
    return;
  }
  b -= NB_OUT;
  {
    int e = b * 256 + t;
    if (e < NE) atomicAdd(&cnt[dstp[e]], 1);
  }
}

// ---------------- CSR scans
__global__ __launch_bounds__(256) void k_scan1(const int* __restrict__ cnt, int* __restrict__ row_start,
                                               int* __restrict__ aux) {
  __shared__ int s[256];
  int t = threadIdx.x;
  int i = blockIdx.x * 256 + t;
  int v = (i < NN) ? cnt[i] : 0;
  s[t] = v;
  __syncthreads();
  for (int off = 1; off < 256; off <<= 1) {
    int tv = (t >= off) ? s[t - off] : 0;
    __syncthreads();
    s[t] += tv;
    __syncthreads();
  }
  if (i < NN) row_start[i] = s[t] - v;
  if (t == 255) aux[blockIdx.x] = s[255];
}

__global__ __launch_bounds__(256) void k_scan2(int* __restrict__ aux, int nb) {
  __shared__ int s[256];
  int t = threadIdx.x;
  int v = (t < nb) ? aux[t] : 0;
  s[t] = v;
  __syncthreads();
  for (int off = 1; off < 256; off <<= 1) {
    int tv = (t >= off) ? s[t - off] : 0;
    __syncthreads();
    s[t] += tv;
    __syncthreads();
  }
  if (t < nb) aux[t] = s[t] - v;
}

__global__ __launch_bounds__(256) void k_scan3(int* __restrict__ row_start, const int* __restrict__ aux) {
  int i = blockIdx.x * 256 + threadIdx.x;
  if (i < NN) row_start[i] += aux[i >> 8];
  else if (i == NN) row_start[NN] = NE;
}

// ---------------- scatter: index only
__global__ __launch_bounds__(256) void k_scatter(const int* __restrict__ dst, const int* __restrict__ row_start,
                                                 int* __restrict__ fill, int* __restrict__ perm) {
  int e = blockIdx.x * 256 + threadIdx.x;
  if (e >= NE) return;
  int d = dst[e];
  int p = atomicAdd(&fill[d], 1);
  perm[row_start[d] + p] = e;
}

// ---------------- permute: stream pos, gather e=perm[pos], write srcp + 3 aep planes coalesced
__global__ __launch_bounds__(256) void k_permute(const int* __restrict__ perm, const int* __restrict__ src,
                                                 const float* __restrict__ edge_attr, const float* __restrict__ wea,
                                                 int* __restrict__ srcp, float* __restrict__ aep) {
  __shared__ float wl[3 * EDIM * NHEAD];
  int t = threadIdx.x;
  if (t < 3 * EDIM * NHEAD) wl[t] = wea[t];
  __syncthreads();
  int pos = blockIdx.x * 256 + t;
  if (pos >= NE) return;
  int e = perm[pos];
  srcp[pos] = src[e];
  float ea[EDIM];
#pragma unroll
  for (int k = 0; k < EDIM; k += 4) {
    float4 v = *(const float4*)&edge_attr[(size_t)e * EDIM + k];
    ea[k] = v.x; ea[k + 1] = v.y; ea[k + 2] = v.z; ea[k + 3] = v.w;
  }
#pragma unroll
  for (int l = 0; l < 3; ++l) {
    float a0 = 0.f, a1 = 0.f, a2 = 0.f, a3 = 0.f;
#pragma unroll
    for (int k = 0; k < EDIM; ++k) {
      float ev = ea[k];
      a0 += ev * wl[l * 64 + k * 4 + 0];
      a1 += ev * wl[l * 64 + k * 4 + 1];
      a2 += ev * wl[l * 64 + k * 4 + 2];
      a3 += ev * wl[l * 64 + k * 4 + 3];
    }
    *(float4*)&aep[(size_t)l * NE * 4 + (size_t)pos * 4] = make_float4(a0, a1, a2, a3);
  }
}

// ---------------- conv GEMM via MFMA: full-K staged once, ONE barrier, then barrier-free MFMA.
template <int K>
__global__ __launch_bounds__(256) void k_conv_mfma(const unsigned short* __restrict__ xin,
                                                   const unsigned short* __restrict__ wt,
                                                   const unsigned short* __restrict__ wsd,
                                                   unsigned short* __restrict__ htb,
                                                   float* __restrict__ asrc, float* __restrict__ adst) {
  constexpr int NC = K / 8;            // kc chunks
  constexpr int CA = NC * 128;         // A/B chunk count
  constexpr int CB2 = NC * 16;         // wsd chunk count
  __shared__ unsigned short As[CA * 8];
  __shared__ unsigned short Bs[CA * 8];
  __shared__ unsigned short Bs2[CB2 * 8];
  int t = threadIdx.x;
  int n0 = blockIdx.x * 128;
  int lane = t & 63;
  int wave = t >> 6;
  int wr = wave >> 1, wc = wave & 1;

  floatx4 acc[4][4];
  floatx4 acce[4];
#pragma unroll
  for (int a = 0; a < 4; ++a) {
    acce[a] = (floatx4){0.f, 0.f, 0.f, 0.f};
#pragma unroll
    for (int b = 0; b < 4; ++b) acc[a][b] = (floatx4){0.f, 0.f, 0.f, 0.f};
  }

  // stage everything (coalesced, per-lane gptr)
  for (int c0 = wave * 64; c0 < CA; c0 += 256) {
    int kc = c0 >> 7, row0 = c0 & 127;
    async16(As + (size_t)c0 * 8, xin + ((size_t)kc * NNP + n0 + row0 + lane) * 8);
    async16(Bs + (size_t)c0 * 8, wt + ((size_t)c0 + lane) * 8);
  }
  if (wave * 64 < CB2) async16(Bs2 + (size_t)wave * 64 * 8, wsd + ((size_t)wave * 64 + lane) * 8);

  __syncthreads();  // the only barrier: all staging drained

  int frow = lane & 15, fkc = lane >> 4;
#pragma unroll
  for (int kk = 0; kk < K / 32; ++kk) {
    const unsigned short* ab = As + (size_t)(kk * 4 + fkc) * 128 * 8;
    const unsigned short* bb = Bs + (size_t)(kk * 4 + fkc) * 128 * 8;
    short8 af[4], bf[4], bf2;
#pragma unroll
    for (int ti = 0; ti < 4; ++ti) af[ti] = *(const short8*)(ab + ((size_t)(wr * 64 + frow + ti * 16)) * 8);
#pragma unroll
    for (int tj = 0; tj < 4; ++tj) bf[tj] = *(const short8*)(bb + ((size_t)(wc * 64 + frow + tj * 16)) * 8);
    bf2 = *(const short8*)(Bs2 + ((size_t)(kk * 4 + fkc) * 16 + frow) * 8);
#pragma unroll
    for (int ti = 0; ti < 4; ++ti)
#pragma unroll
      for (int tj = 0; tj < 4; ++tj)
        acc[ti][tj] = __builtin_amdgcn_mfma_f32_16x16x32_bf16(af[ti], bf[tj], acc[ti][tj], 0, 0, 0);
    if (wc == 0) {
#pragma unroll
      for (int ti = 0; ti < 4; ++ti)
        acce[ti] = __builtin_amdgcn_mfma_f32_16x16x32_bf16(af[ti], bf2, acce[ti], 0, 0, 0);
    }
  }

  int q = lane & 15;
  int colg = wc * 64 + q;
#pragma unroll
  for (int ti = 0; ti < 4; ++ti) {
    int rowb = n0 + wr * 64 + ti * 16 + (lane >> 4) * 4;
#pragma unroll
    for (int r = 0; r < 4; ++r) {
      int row = rowb + r;
      if (row < NN) {
        htb[(size_t)row * HC + colg] = f2bf(acc[ti][0][r]);
        htb[(size_t)row * HC + colg + 16] = f2bf(acc[ti][1][r]);
        htb[(size_t)row * HC + colg + 32] = f2bf(acc[ti][2][r]);
        htb[(size_t)row * HC + colg + 48] = f2bf(acc[ti][3][r]);
        if (wc == 0 && q < 8) {
          float v = acce[ti][r];
          if (q < 4) asrc[row * 4 + q] = v;
          else adst[row * 4 + (q - 4)] = v;
        }
      }
    }
  }
}

// ---------------- fused alpha + softmax + aggregate. One wave per node, NO block barriers.
__global__ __launch_bounds__(256) void k_aggregate(
    const unsigned short* __restrict__ htb, const int* __restrict__ srcp,
    const float* __restrict__ aep, const float* __restrict__ asrc, const float* __restrict__ adst,
    const int* __restrict__ row_start, const float* __restrict__ bias,
    unsigned short* __restrict__ XBp, int kcoff) {
  __shared__ float exs[4][MAXCH][4];
  int t = threadIdx.x;
  int lane = t & 63, wid = t >> 6;
  int n = blockIdx.x * 4 + wid;
  if (n >= NN) return;  // whole wave exits; no barriers in this kernel
  int rs = row_start[n], re = row_start[n + 1];
  int nchunk = (re - rs + MAXCH - 1) / MAXCH;
  int q = lane & 15, g = lane >> 4;
  int h = q >> 2;
  float4 ad4 = *(const float4*)&adst[n * 4];
  float acc[8];
#pragma unroll
  for (int j = 0; j < 8; ++j) acc[j] = 0.f;
  float d0 = 0.f, d1 = 0.f, d2 = 0.f, d3 = 0.f;

  for (int cc = 0; cc < nchunk; ++cc) {
    int base = rs + cc * MAXCH;
    int m = re - base;
    if (m > MAXCH) m = MAXCH;
    if (lane < m) {
      int i = base + lane;
      int s = srcp[i];
      float4 ae = *(const float4*)&aep[(size_t)i * 4];
      float4 as4 = *(const float4*)&asrc[s * 4];
      float4 ex;
      ex.x = __expf(lrelu(as4.x + ad4.x + ae.x, 0.2f));
      ex.y = __expf(lrelu(as4.y + ad4.y + ae.y, 0.2f));
      ex.z = __expf(lrelu(as4.z + ad4.z + ae.z, 0.2f));
      ex.w = __expf(lrelu(as4.w + ad4.w + ae.w, 0.2f));
      *(float4*)&exs[wid][lane][0] = ex;
      d0 += ex.x; d1 += ex.y; d2 += ex.z; d3 += ex.w;
    }
    __threadfence_block();  // wave-local LDS writes visible (no s_barrier)
    int iters = (m + 7) >> 3;
    for (int kk = 0; kk < iters; ++kk) {
      int ii0 = kk * 8 + g;
      int ii1 = ii0 + 4;
      int i0 = base + ((ii0 < m) ? ii0 : 0);
      int i1 = base + ((ii1 < m) ? ii1 : 0);
      int s0 = srcp[i0];
      int s1 = srcp[i1];
      uint4 h0 = *(const uint4*)(htb + (size_t)s0 * HC + q * 8);
      uint4 h1 = *(const uint4*)(htb + (size_t)s1 * HC + q * 8);
      float w0 = (ii0 < m) ? exs[wid][ii0][h] : 0.f;
      float w1 = (ii1 < m) ? exs[wid][ii1][h] : 0.f;
      acc[0] += w0 * bflo(h0.x) + w1 * bflo(h1.x);
      acc[1] += w0 * bfhi(h0.x) + w1 * bfhi(h1.x);
      acc[2] += w0 * bflo(h0.y) + w1 * bflo(h1.y);
      acc[3] += w0 * bfhi(h0.y) + w1 * bfhi(h1.y);
      acc[4] += w0 * bflo(h0.z) + w1 * bflo(h1.z);
      acc[5] += w0 * bfhi(h0.z) + w1 * bfhi(h1.z);
      acc[6] += w0 * bflo(h0.w) + w1 * bflo(h1.w);
      acc[7] += w0 * bfhi(h0.w) + w1 * bfhi(h1.w);
    }
    __threadfence_block();  // reads done before next chunk overwrites exs
  }

#pragma unroll
  for (int mm = 1; mm < 64; mm <<= 1) {
    d0 += __shfl_xor(d0, mm, 64);
    d1 += __shfl_xor(d1, mm, 64);
    d2 += __shfl_xor(d2, mm, 64);
    d3 += __shfl_xor(d3, mm, 64);
  }
#pragma unroll
  for (int j = 0; j < 8; ++j) {
    acc[j] += __shfl_xor(acc[j], 16, 64);
    acc[j] += __shfl_xor(acc[j], 32, 64);
  }
  if (g == 0) {
    float dh = (h == 0) ? d0 : ((h == 1) ? d1 : ((h == 2) ? d2 : d3));
    float inv = 1.f / (dh + 1e-16f);
    unsigned int w[4];
#pragma unroll
    for (int j = 0; j < 4; ++j) {
      float v0 = acc[2 * j] * inv + bias[q * 8 + 2 * j];
      float v1 = acc[2 * j + 1] * inv + bias[q * 8 + 2 * j + 1];
      w[j] = (unsigned int)f2bf(v0) | ((unsigned int)f2bf(v1) << 16);
    }
    *(uint4*)&XBp[((size_t)(kcoff + q) * NNP + n) * 8] = make_uint4(w[0], w[1], w[2], w[3]);
  }
}

// ---------------- global add pool from XB kc 32..47 (= h3)
__global__ __launch_bounds__(128) void k_pool(const unsigned short* __restrict__ XBp, const int* __restrict__ gs,
                                              float* __restrict__ hpool) {
  int g = blockIdx.x;
  int j = threadIdx.x;
  int kc = 32 + (j >> 3), sb = j & 7;
  int s = gs[g], e = gs[g + 1];
  float acc = 0.f;
  for (int i = s; i < e; ++i) acc += bflo((unsigned int)XBp[((size_t)kc * NNP + i) * 8 + sb]);
  hpool[(size_t)g * HC + j] = acc;
}

// ---------------- ph[g,0:512] = hpool[g,0:128] @ lw1[384:512, 0:512]
__global__ __launch_bounds__(256) void k_pool_gemm(const float* __restrict__ hpool, const float* __restrict__ lw1,
                                                   float* __restrict__ ph) {
  __shared__ float hp[16][128];
  int t = threadIdx.x;
  int j0 = blockIdx.x * 128;
  int g0 = blockIdx.y * 16;
  int jj = t & 127, gg = t >> 7;
#pragma unroll
  for (int i = 0; i < 8; ++i) {
    int q = t + 256 * i;
    int row = q >> 7, col = q & 127;
    hp[row][col] = hpool[(size_t)(g0 + row) * HC + col];
  }
  __syncthreads();
  float acc[8];
#pragma unroll
  for (int i = 0; i < 8; ++i) acc[i] = 0.f;
  for (int k = 0; k < HC; ++k) {
    float wv = lw1[(size_t)(384 + k) * 512 + j0 + jj];
#pragma unroll
    for (int gi = 0; gi < 8; ++gi) acc[gi] += hp[gg + 2 * gi][k] * wv;
  }
#pragma unroll
  for (int gi = 0; gi < 8; ++gi) ph[(size_t)(g0 + gg + 2 * gi) * 512 + j0 + jj] = acc[gi];
}

// ---------------- fused MLP via bf16 MFMA: LDS-FREE, BARRIER-FREE.
// A/B fragments loaded per-lane directly from k-major global images (4x256B segments per
// load inst). A (HBM) double-buffered across half-steps; B (L2-resident) just-in-time.
// No __syncthreads -> compiler emits fine-grained per-use s_waitcnt vmcnt(N).
__global__ __launch_bounds__(256, 2) void k_mlp_mfma(
    const unsigned short* __restrict__ XBp, const unsigned short* __restrict__ lw1img,
    const float* __restrict__ ph, const int* __restrict__ batch,
    const float* __restrict__ lb1, const float* __restrict__ lw2,
    float* __restrict__ out) {
  int t = threadIdx.x;
  int jh = blockIdx.x;         // 0,1
  int n0 = blockIdx.y * 128;
  int lane = t & 63;
  int wave = t >> 6;
  int wr = wave >> 1, wc = wave & 1;
  const unsigned short* bimg = lw1img + (size_t)jh * 48 * 256 * 8;

  floatx4 acc[4][8];
#pragma unroll
  for (int a = 0; a < 4; ++a)
#pragma unroll
    for (int b = 0; b < 8; ++b) acc[a][b] = (floatx4){0.f, 0.f, 0.f, 0.f};

  // per-lane fragment base addresses (lane -> (kc_local = lane>>4, row/col = lane&15))
  const unsigned short* abase = XBp + (((size_t)(lane >> 4)) * NNP + n0 + wr * 64 + (lane & 15)) * 8;
  const unsigned short* bbase = bimg + (((size_t)(lane >> 4)) * 256 + wc * 128 + (lane & 15)) * 8;
  const size_t akk = (size_t)4 * NNP * 8;  // A stride per 32-k step
  const size_t bkk = (size_t)4 * 256 * 8;  // B stride per 32-k step

  short8 af0[4], af1[4], bfE[8], bfO[8];
  // preload A for kk=0
#pragma unroll
  for (int ti = 0; ti < 4; ++ti) af0[ti] = *(const short8*)(abase + (size_t)ti * 16 * 8);

#pragma unroll
  for (int kk2 = 0; kk2 < 6; ++kk2) {
    const unsigned short* ae_ = abase + (size_t)(2 * kk2) * akk;
    const unsigned short* be_ = bbase + (size_t)(2 * kk2) * bkk;
    // B for even step + A prefetch for odd step
#pragma unroll
    for (int tj = 0; tj < 8; ++tj) bfE[tj] = *(const short8*)(be_ + (size_t)tj * 16 * 8);
#pragma unroll
    for (int ti = 0; ti < 4; ++ti) af1[ti] = *(const short8*)(ae_ + akk + (size_t)ti * 16 * 8);
#pragma unroll
    for (int ti = 0; ti < 4; ++ti)
#pragma unroll
      for (int tj = 0; tj < 8; ++tj)
        acc[ti][tj] = __builtin_amdgcn_mfma_f32_16x16x32_bf16(af0[ti], bfE[tj], acc[ti][tj], 0, 0, 0);
    // B for odd step + A prefetch for next even step
#pragma unroll
    for (int tj = 0; tj < 8; ++tj) bfO[tj] = *(const short8*)(be_ + bkk + (size_t)tj * 16 * 8);
    if (kk2 < 5) {
#pragma unroll
      for (int ti = 0; ti < 4; ++ti) af0[ti] = *(const short8*)(ae_ + 2 * akk + (size_t)ti * 16 * 8);
    }
#pragma unroll
    for (int ti = 0; ti < 4; ++ti)
#pragma unroll
      for (int tj = 0; tj < 8; ++tj)
        acc[ti][tj] = __builtin_amdgcn_mfma_f32_16x16x32_bf16(af1[ti], bfO[tj], acc[ti][tj], 0, 0, 0);
  }

  int colg = jh * 256 + wc * 128 + (lane & 15);
#pragma unroll
  for (int ti = 0; ti < 4; ++ti) {
    int rowb = n0 + wr * 64 + ti * 16 + (lane >> 4) * 4;
#pragma unroll
    for (int r = 0; r < 4; ++r) {
      int row = rowb + r;
      int rc = (row < NN) ? row : 0;
      int bg = batch[rc];
      float partial = 0.f;
#pragma unroll
      for (int tj = 0; tj < 8; ++tj) {
        int j = colg + tj * 16;
        float v = acc[ti][tj][r] + ph[(size_t)bg * 512 + j] + lb1[j];
        partial += lrelu(v, 0.01f) * lw2[j];
      }
#pragma unroll
      for (int m = 1; m < 16; m <<= 1) partial += __shfl_xor(partial, m, 16);
      if ((lane & 15) == 0 && row < NN) atomicAdd(&out[row], partial);
    }
  }
}

extern "C" void kernel_launch(void* const* d_in, const int* in_sizes, int n_in,
                              void* d_out, int out_size, void* d_ws, size_t ws_size,
                              hipStream_t stream) {
  const float* x = (const float*)d_in[0];
  const int* edge_index = (const int*)d_in[1];
  const int* src = edge_index;
  const int* dstp = edge_index + NE;
  const float* edge_attr = (const float*)d_in[2];
  const int* batch = (const int*)d_in[3];
  const float* W[3] = {(const float*)d_in[4], (const float*)d_in[10], (const float*)d_in[16]};
  const float* as_[3] = {(const float*)d_in[5], (const float*)d_in[11], (const float*)d_in[17]};
  const float* ad_[3] = {(const float*)d_in[6], (const float*)d_in[12], (const float*)d_in[18]};
  const float* We_[3] = {(const float*)d_in[7], (const float*)d_in[13], (const float*)d_in[19]};
  const float* ae_[3] = {(const float*)d_in[8], (const float*)d_in[14], (const float*)d_in[20]};
  const float* b_[3] = {(const float*)d_in[9], (const float*)d_in[15], (const float*)d_in[21]};
  const float* lw1 = (const float*)d_in[22];
  const float* lb1 = (const float*)d_in[23];
  const float* lw2 = (const float*)d_in[24];
  const float* lb2 = (const float*)d_in[25];
  float* out = (float*)d_out;

  // workspace carve-up (floats unless noted)
  float* f = (float*)d_ws;
  size_t o = 0;
  float* asrc = f + o;  o += (size_t)NN * NHEAD;
  float* adst = f + o;  o += (size_t)NN * NHEAD;
  float* wea = f + o;   o += 256;
  float* hpool = f + o; o += (size_t)NG * HC;
  float* aep = f + o;   o += (size_t)3 * NE * 4;
  // xb0 (k-major [8][NNP][8] bf16) overlaid with ph (fp32 [NG][512]): xb0 dead before ph written
  unsigned short* xb0 = (unsigned short*)(f + o);
  float* ph = (float*)xb0;
  o += (size_t)8 * NNP * 8 / 2;
  unsigned short* htb = (unsigned short*)(f + o);   o += (size_t)NN * HC / 2;
  unsigned short* XB = (unsigned short*)(f + o);    o += (size_t)48 * NNP * 8 / 2;
  unsigned short* wtb = (unsigned short*)(f + o);   o += (size_t)(128 * 64 + 2 * 128 * 128) / 2;
  unsigned short* lw1img = (unsigned short*)(f + o); o += (size_t)2 * 48 * 256 * 8 / 2;
  unsigned short* wsdb = (unsigned short*)(f + o);  o += (size_t)3 * 2048 / 2;
  int* row_start = (int*)(f + o);
  int* cnt = row_start + (NN + 1);
  int* fill = cnt + NN;
  int* aux = fill + NN;
  int* gs = aux + 256;
  int* perm = gs + (NG + 1);
  int* srcp = perm + NE;

  const int NB = (NN + 255) / 256;
  const int EB = (NE + 255) / 256;

  hipMemsetAsync(cnt, 0, (size_t)2 * NN * sizeof(int), stream);  // cnt + fill

  k_prep<<<PREP_BLOCKS, 256, 0, stream>>>(
      We_[0], ae_[0], We_[1], ae_[1], We_[2], ae_[2], wea,
      W[0], as_[0], ad_[0], W[1], as_[1], ad_[1], W[2], as_[2], ad_[2], wsdb,
      lw1, lw1img, wtb, x, xb0, batch, gs, out, lb2, dstp, cnt);
  k_scan1<<<NB, 256, 0, stream>>>(cnt, row_start, aux);
  k_scan2<<<1, 256, 0, stream>>>(aux, NB);
  k_scan3<<<NB, 256, 0, stream>>>(row_start, aux);
  k_scatter<<<EB, 256, 0, stream>>>(dstp, row_start, fill, perm);
  k_permute<<<EB, 256, 0, stream>>>(perm, src, edge_attr, wea, srcp, aep);

  const int CONVB = NNP / 128;  // 391
  unsigned short* wt_l[3] = {wtb, wtb + 8192, wtb + 24576};
  for (int l = 0; l < 3; ++l) {
    unsigned short* wsd_l = wsdb + (size_t)l * 2048;
    const unsigned short* xin = (l == 0) ? xb0 : (XB + (size_t)(l - 1) * 16 * NNP * 8);
    if (l == 0)
      k_conv_mfma<64><<<CONVB, 256, 0, stream>>>(xin, wt_l[0], wsd_l, htb, asrc, adst);
    else
      k_conv_mfma<128><<<CONVB, 256, 0, stream>>>(xin, wt_l[l], wsd_l, htb, asrc, adst);
    k_aggregate<<<(NN + 3) / 4, 256, 0, stream>>>(htb, srcp, aep + (size_t)l * NE * 4, asrc, adst,
                                                  row_start, b_[l], XB, l * 16);
  }

  k_pool<<<NG, 128, 0, stream>>>(XB, gs, hpool);
  k_pool_gemm<<<dim3(4, NG / 16), 256, 0, stream>>>(hpool, lw1, ph);
  k_mlp_mfma<<<dim3(2, NNP / 128), 256, 0, stream>>>(XB, lw1img, ph, batch, lb1, lw2, out);
}